// Round 8
// baseline (5050.955 us; speedup 1.0000x reference)
//
#include <hip/hip_runtime.h>
#include <hip/hip_bf16.h>
#include <stdint.h>

typedef unsigned short u16;
typedef __bf16 bf16x8 __attribute__((ext_vector_type(8)));
typedef float f32x4 __attribute__((ext_vector_type(4)));

// ---------- helpers ----------
__device__ __forceinline__ u16 f2bf(float f) {
  uint32_t u = __float_as_uint(f);
  u = (u + 0x7FFFu + ((u >> 16) & 1u)) >> 16;  // RNE
  return (u16)u;
}
__device__ __forceinline__ float bf2f(u16 x) {
  return __uint_as_float(((uint32_t)x) << 16);
}
__device__ __forceinline__ float blo(uint32_t w) { return __uint_as_float(w << 16); }
__device__ __forceinline__ float bhi(uint32_t w) { return __uint_as_float(w & 0xFFFF0000u); }

__device__ __forceinline__ void gl2lds16(const void* g, void* l) {
  __builtin_amdgcn_global_load_lds(
      (const __attribute__((address_space(1))) void*)g,
      (__attribute__((address_space(3))) void*)l, 16, 0, 0);
}

// ---------- f32 -> bf16 array convert (n4 = count/4, exact) ----------
__global__ void cvt_bf16_arr(const float* __restrict__ in, u16* __restrict__ out, int n4) {
  int i = blockIdx.x * blockDim.x + threadIdx.x;
  if (i >= n4) return;
  float4 v = ((const float4*)in)[i];
  ushort4 o;
  o.x = f2bf(v.x); o.y = f2bf(v.y); o.z = f2bf(v.z); o.w = f2bf(v.w);
  ((ushort4*)out)[i] = o;
}

// ---------- pack Whh[j][k] -> u32 {bf16(k),bf16(k+1)} at [k/2][j] ----------
__global__ void pack_whh(const float* __restrict__ W, uint32_t* __restrict__ out) {
  int idx = blockIdx.x * 256 + threadIdx.x;   // 512 blocks * 256 thr
  int p = idx >> 9, j = idx & 511;
  float a = W[j * 512 + 2 * p];
  float b = W[j * 512 + 2 * p + 1];
  out[p * 512 + j] = (uint32_t)f2bf(a) | ((uint32_t)f2bf(b) << 16);
}

// ---------- gather token embeddings -> bf16 rows (B-major, 128 per batch) ----------
__global__ void gather_embed(const int* __restrict__ tok, const float* __restrict__ embed,
                             u16* __restrict__ out, int tokStride) {
  int m = blockIdx.x;          // 0..4095 : b*128 + pos
  int t = threadIdx.x;         // 128 threads, 4 floats each
  int token = tok[(m >> 7) * tokStride + (m & 127)];
  float4 v = ((const float4*)(embed + (long)token * 512))[t];
  ushort4 o;
  o.x = f2bf(v.x); o.y = f2bf(v.y); o.z = f2bf(v.z); o.w = f2bf(v.w);
  ((ushort4*)(out + (long)m * 512))[t] = o;
}

// ---------- bf16 MFMA GEMM: C[M,N] = A[M,K] * B[N,K]^T (+bias[n]) ----------
// (round-1 verbatim; 128x128 tile, BK=32, 4 waves, 16x16x32 MFMA)
__global__ __launch_bounds__(256) void gemm_bf16_kernel(
    const u16* __restrict__ A, const u16* __restrict__ B,
    const float* __restrict__ bias, float* __restrict__ C,
    int M, int N, int K) {
  __shared__ __align__(16) u16 As[4096];
  __shared__ __align__(16) u16 Bs[4096];
  const int tid = threadIdx.x;
  const int lane = tid & 63;
  const int wv = tid >> 6;
  const int wr = wv >> 1, wc = wv & 1;
  const long m0 = (long)blockIdx.y * 128;
  const long n0 = (long)blockIdx.x * 128;

  f32x4 zero = {0.f, 0.f, 0.f, 0.f};
  f32x4 acc[4][4];
#pragma unroll
  for (int i = 0; i < 4; ++i)
#pragma unroll
    for (int j = 0; j < 4; ++j) acc[i][j] = zero;

  const u16* Ag = A + (m0 + (tid >> 2)) * (long)K + (tid & 3) * 8;
  const u16* Bg = B + (n0 + (tid >> 2)) * (long)K + (tid & 3) * 8;
  const u16* Ag2 = Ag + 64 * (long)K;
  const u16* Bg2 = Bg + 64 * (long)K;
  u16* AsW = As + (tid >> 6) * 512;   // wave-uniform LDS base
  u16* BsW = Bs + (tid >> 6) * 512;
  const int ra = (wr * 64 + (lane & 15)) * 32 + (lane >> 4) * 8;
  const int rb = (wc * 64 + (lane & 15)) * 32 + (lane >> 4) * 8;

  for (int kt = 0; kt < K; kt += 32) {
    __syncthreads();                         // previous-tile reads done
    gl2lds16(Ag + kt, AsW);                  // rows 0..63
    gl2lds16(Ag2 + kt, AsW + 2048);          // rows 64..127
    gl2lds16(Bg + kt, BsW);
    gl2lds16(Bg2 + kt, BsW + 2048);
    __syncthreads();                         // barrier drains vmcnt
    bf16x8 af[4], bfr[4];
#pragma unroll
    for (int i = 0; i < 4; ++i) af[i] = *(const bf16x8*)&As[ra + i * 512];
#pragma unroll
    for (int j = 0; j < 4; ++j) bfr[j] = *(const bf16x8*)&Bs[rb + j * 512];
#pragma unroll
    for (int i = 0; i < 4; ++i)
#pragma unroll
      for (int j = 0; j < 4; ++j)
        acc[i][j] = __builtin_amdgcn_mfma_f32_16x16x32_bf16(af[i], bfr[j], acc[i][j], 0, 0, 0);
  }

#pragma unroll
  for (int i = 0; i < 4; ++i) {
    const long row = m0 + wr * 64 + i * 16 + ((lane >> 4) << 2);
#pragma unroll
    for (int j = 0; j < 4; ++j) {
      const long col = n0 + wc * 64 + j * 16 + (lane & 15);
      const float bv = bias ? bias[col] : 0.f;
#pragma unroll
      for (int r = 0; r < 4; ++r)
        C[(row + r) * (long)N + col] = acc[i][j][r] + bv;
    }
  }
}

// ---------- RNN recurrence v3: three-tier weights sized to the PROVEN 128-VGPR cap ----------
// Rounds 3-7 showed: this kernel never gets >128 VGPRs regardless of
// __launch_bounds__ spelling; a 192-pair register file spills ~13MB/launch.
// New split, thread j owns row Whh[j][:] (256 bf16-pairs):
//   pairs   0..79  : 20 named uint4 = 80 VGPRs  (~116 total pressure <= 128)
//   pairs  80..143 : LDS wlds[64][512] (128 KB, 4B lane stride, conflict-free)
//   pairs 144..255 : streamed from L2 each step (7 x 16 coalesced dword loads;
//                    WhhP is 512KB -> XCD-L2 resident; r1 proved this pattern)
// h stays f32 in LDS (broadcast float4 reads). Numerics = round-3 passing path.

#define FOR20(M) \
  M(0) M(1) M(2) M(3) M(4) M(5) M(6) M(7) M(8) M(9) \
  M(10) M(11) M(12) M(13) M(14) M(15) M(16) M(17) M(18) M(19)

__global__ __launch_bounds__(512) void rnn_core(
    const float* __restrict__ pre,            // [B*128][512] f32
    const uint32_t* __restrict__ WhhP,        // [256][512] bf16-pairs [p][j]
    const float* __restrict__ bih, const float* __restrict__ bhh,
    const float* __restrict__ h0,             // [B][512] f32 or null (zeros)
    float* __restrict__ hOutF, long ldF,      // f32 h out (or null)
    u16* __restrict__ hOutB, long ldB_,       // bf16 h out
    float* __restrict__ hLast)                // [B][512] f32 or null
{
  const int b = blockIdx.x, j = threadIdx.x;
  __shared__ __align__(16) float h_sh[512];
  __shared__ uint32_t wlds[64][512];          // pairs 80..143: [p-80][j]
  const uint32_t* Wp = WhhP + j;
  // pairs 0..79 in 20 named uint4 registers (coalesced dword loads)
#define LDW_(i) uint4 wr##i; \
  wr##i.x = Wp[(long)(4*(i)+0) * 512]; wr##i.y = Wp[(long)(4*(i)+1) * 512]; \
  wr##i.z = Wp[(long)(4*(i)+2) * 512]; wr##i.w = Wp[(long)(4*(i)+3) * 512];
  FOR20(LDW_)
#undef LDW_
#pragma unroll
  for (int p = 0; p < 64; ++p) wlds[p][j] = Wp[(long)(80 + p) * 512];
  const float biasj = bih[j] + bhh[j];
  h_sh[j] = h0 ? h0[(long)b * 512 + j] : 0.f;
  const float* preB = pre + (long)b * 128 * 512 + j;
  __syncthreads();

  for (int t = 0; t < 128; ++t) {
    const float4* H4 = (const float4*)h_sh;
    float a0 = 0.f, a1 = 0.f, a2 = 0.f, a3 = 0.f;
    // ---- tier 1: pairs 0..79 from named VGPRs (k = 0..159, H4[0..39]) ----
#define ACC_(g) { \
    float4 ha = H4[2*(g)]; \
    float4 hb = H4[2*(g)+1]; \
    a0 += ha.x * blo(wr##g.x) + ha.y * bhi(wr##g.x); \
    a1 += ha.z * blo(wr##g.y) + ha.w * bhi(wr##g.y); \
    a2 += hb.x * blo(wr##g.z) + hb.y * bhi(wr##g.z); \
    a3 += hb.z * blo(wr##g.w) + hb.w * bhi(wr##g.w); }
    FOR20(ACC_)
#undef ACC_
    // ---- tier 2: pairs 80..143 from LDS (k = 160..287, H4[40..71]) ----
#pragma unroll
    for (int g = 0; g < 16; ++g) {
      float4 ha = H4[40 + 2 * g];
      float4 hb = H4[40 + 2 * g + 1];
      uint32_t w0 = wlds[4 * g][j], w1 = wlds[4 * g + 1][j];
      uint32_t w2 = wlds[4 * g + 2][j], w3 = wlds[4 * g + 3][j];
      a0 += ha.x * blo(w0) + ha.y * bhi(w0);
      a1 += ha.z * blo(w1) + ha.w * bhi(w1);
      a2 += hb.x * blo(w2) + hb.y * bhi(w2);
      a3 += hb.z * blo(w3) + hb.w * bhi(w3);
    }
    // ---- tier 3: pairs 144..255 streamed from L2 (k = 288..511, H4[72..127]) ----
#pragma unroll
    for (int c = 0; c < 7; ++c) {
      uint32_t s[16];
#pragma unroll
      for (int i = 0; i < 16; ++i) s[i] = Wp[(long)(144 + 16 * c + i) * 512];
#pragma unroll
      for (int i = 0; i < 8; ++i) {
        float4 hv = H4[72 + 8 * c + i];
        if (i & 1) {
          a2 += hv.x * blo(s[2 * i]) + hv.y * bhi(s[2 * i]);
          a3 += hv.z * blo(s[2 * i + 1]) + hv.w * bhi(s[2 * i + 1]);
        } else {
          a0 += hv.x * blo(s[2 * i]) + hv.y * bhi(s[2 * i]);
          a1 += hv.z * blo(s[2 * i + 1]) + hv.w * bhi(s[2 * i + 1]);
        }
      }
    }
    float h = tanhf(preB[(long)t * 512] + biasj + ((a0 + a1) + (a2 + a3)));
    __syncthreads();                          // all h_sh reads done
    h_sh[j] = h;
    if (hOutF) hOutF[((long)b * 128 + t) * ldF + j] = h;
    hOutB[((long)b * 128 + t) * ldB_ + j] = f2bf(h);
    if (hLast && t == 127) hLast[(long)b * 512 + j] = h;
    __syncthreads();                          // new h visible
  }
}

// ---------- fused attention: scores -> softmax -> att out -> ctx (all f32) ----------
// grid (32 b, 8 t-groups), block 1024 (16 waves, wave w owns t = y*16+w)
__global__ __launch_bounds__(1024) void attn_fused(
    const u16* __restrict__ hcat,        // bf16, dec_h in cols 0..511
    const float* __restrict__ encT,      // [B][128 s][512] f32
    const float* __restrict__ encBsh,    // [B][128 s][512] f32
    u16* __restrict__ hcatW,             // write ctx into cols 512..1023 (bf16)
    float* __restrict__ attOut)          // [B][128 s][128 t] f32
{
  const int b = blockIdx.x;
  const int w = threadIdx.x >> 6, lane = threadIdx.x & 63;
  const int t = blockIdx.y * 16 + w;
  __shared__ float at[16][128];

  // dec_h row t -> registers (bf16 -> f32)
  float hreg[8];
  const u16* hrow = hcat + ((long)b * 128 + t) * 1024;
#pragma unroll
  for (int i = 0; i < 8; ++i) hreg[i] = bf2f(hrow[lane + i * 64]);

  // scores: score[s] = dec_h[t] . enc_t[s]
  const float* et = encT + (long)b * 128 * 512;
  for (int s = 0; s < 128; ++s) {
    const float* row = et + (long)s * 512;
    float a = 0.f;
#pragma unroll
    for (int i = 0; i < 8; ++i) a += hreg[i] * row[lane + i * 64];
#pragma unroll
    for (int o = 32; o; o >>= 1) a += __shfl_xor(a, o, 64);
    if (lane == 0) at[w][s] = a;
  }
  __syncthreads();

  // softmax over s (per wave, 2 values per lane)
  float s0 = at[w][lane], s1 = at[w][lane + 64];
  float mx = fmaxf(s0, s1);
#pragma unroll
  for (int o = 32; o; o >>= 1) mx = fmaxf(mx, __shfl_xor(mx, o, 64));
  float e0 = __expf(s0 - mx), e1 = __expf(s1 - mx);
  float sm = e0 + e1;
#pragma unroll
  for (int o = 32; o; o >>= 1) sm += __shfl_xor(sm, o, 64);
  float inv = 1.f / sm;
  e0 *= inv; e1 *= inv;
  at[w][lane] = e0;
  at[w][lane + 64] = e1;
  __syncthreads();

  // att output: att[b][s][t]
  attOut[(long)b * 16384 + (long)lane * 128 + t] = e0;
  attOut[(long)b * 16384 + (long)(lane + 64) * 128 + t] = e1;

  // ctx[t][:] = sum_s attn[s] * enc_bsh[s][:]
  float acc[8] = {0.f, 0.f, 0.f, 0.f, 0.f, 0.f, 0.f, 0.f};
  const float* eb = encBsh + (long)b * 128 * 512;
  for (int s = 0; s < 128; ++s) {
    float ws = at[w][s];
    const float* row = eb + (long)s * 512;
#pragma unroll
    for (int i = 0; i < 8; ++i) acc[i] += ws * row[lane + i * 64];
  }
  u16* crow = hcatW + ((long)b * 128 + t) * 1024 + 512;
#pragma unroll
  for (int i = 0; i < 8; ++i) crow[lane + i * 64] = f2bf(acc[i]);
}

// ---------- launcher ----------
extern "C" void kernel_launch(void* const* d_in, const int* in_sizes, int n_in,
                              void* d_out, int out_size, void* d_ws, size_t ws_size,
                              hipStream_t stream) {
  (void)in_sizes; (void)n_in; (void)out_size; (void)ws_size;
  const int*   source = (const int*)d_in[0];
  const int*   target = (const int*)d_in[1];
  const float* embed  = (const float*)d_in[2];
  const float* encWih = (const float*)d_in[3];
  const float* encWhh = (const float*)d_in[4];
  const float* encBih = (const float*)d_in[5];
  const float* encBhh = (const float*)d_in[6];
  const float* decWih = (const float*)d_in[7];
  const float* decWhh = (const float*)d_in[8];
  const float* decBih = (const float*)d_in[9];
  const float* decBhh = (const float*)d_in[10];
  const float* attnW  = (const float*)d_in[11];
  const float* attnB  = (const float*)d_in[12];
  const float* outW   = (const float*)d_in[13];
  const float* outB   = (const float*)d_in[14];

  float* out_logits = (float*)d_out;
  float* out_att = out_logits + (long)32 * 128 * 32000;

  char* wsb = (char*)d_ws;
  size_t off = 0;
  auto alloc = [&](size_t bytes) {
    char* p = wsb + off;
    off += (bytes + 255) & ~(size_t)255;
    return p;
  };
  u16*      encA   = (u16*)alloc(4096l * 512 * 2);
  u16*      decA   = (u16*)alloc(4096l * 512 * 2);
  u16*      wihE   = (u16*)alloc(512l * 512 * 2);
  u16*      wihD   = (u16*)alloc(512l * 512 * 2);
  u16*      attnWb = (u16*)alloc(512l * 512 * 2);
  uint32_t* whhPe  = (uint32_t*)alloc(256l * 512 * 4);
  uint32_t* whhPd  = (uint32_t*)alloc(256l * 512 * 4);
  u16*      outWb  = (u16*)alloc(32000l * 1024 * 2);
  float*    preE   = (float*)alloc(4096l * 512 * 4);
  float*    preD   = (float*)alloc(4096l * 512 * 4);
  float*    encBsh = (float*)alloc(4096l * 512 * 4);
  u16*      encBf  = (u16*)alloc(4096l * 512 * 2);
  float*    encT   = (float*)alloc(4096l * 512 * 4);
  float*    hlast  = (float*)alloc(32l * 512 * 4);
  u16*      hcat   = (u16*)alloc(4096l * 1024 * 2);

  // weight conversions (independent)
  cvt_bf16_arr<<<256, 256, 0, stream>>>(encWih, wihE, 65536);
  cvt_bf16_arr<<<256, 256, 0, stream>>>(decWih, wihD, 65536);
  cvt_bf16_arr<<<256, 256, 0, stream>>>(attnW, attnWb, 65536);
  cvt_bf16_arr<<<32000, 256, 0, stream>>>(outW, outWb, 8192000);
  pack_whh<<<512, 256, 0, stream>>>(encWhh, whhPe);
  pack_whh<<<512, 256, 0, stream>>>(decWhh, whhPd);
  // embedding gathers
  gather_embed<<<4096, 128, 0, stream>>>(source, embed, encA, 128);
  gather_embed<<<4096, 128, 0, stream>>>(target, embed, decA, 129);
  // pre-activations for all timesteps: x @ Wih^T (f32 out)
  gemm_bf16_kernel<<<dim3(4, 32), 256, 0, stream>>>(encA, wihE, (const float*)nullptr, preE, 4096, 512, 512);
  gemm_bf16_kernel<<<dim3(4, 32), 256, 0, stream>>>(decA, wihD, (const float*)nullptr, preD, 4096, 512, 512);
  // encoder recurrence (h0=0): writes enc_bsh f32, encBf bf16, hlast f32
  rnn_core<<<32, 512, 0, stream>>>(preE, whhPe, encBih, encBhh,
      (const float*)nullptr, encBsh, 512, encBf, 512, hlast);
  // enc_t = enc_h @ attn_W^T + attn_b (f32 out)
  gemm_bf16_kernel<<<dim3(4, 32), 256, 0, stream>>>(encBf, attnWb, attnB, encT, 4096, 512, 512);
  // decoder recurrence (h0 = enc last): writes dec_h bf16 into hcat left half
  rnn_core<<<32, 512, 0, stream>>>(preD, whhPd, decBih, decBhh,
      hlast, (float*)nullptr, 512, hcat, 1024, (float*)nullptr);
  // fused attention: scores->softmax->att out->ctx (f32), ctx bf16 -> hcat right half
  attn_fused<<<dim3(32, 8), 1024, 0, stream>>>(hcat, encT, encBsh, hcat, out_att);
  // logits = [h,ctx] @ out_W^T + out_b  -> d_out (B,T,C) f32
  gemm_bf16_kernel<<<dim3(250, 32), 256, 0, stream>>>(hcat, outWb, outB, out_logits, 4096, 32000, 1024);
}

// Round 9
// 3260.888 us; speedup vs baseline: 1.5490x; 1.5490x over previous
//
#include <hip/hip_runtime.h>
#include <hip/hip_bf16.h>
#include <stdint.h>

typedef unsigned short u16;
typedef __bf16 bf16x8 __attribute__((ext_vector_type(8)));
typedef float f32x4 __attribute__((ext_vector_type(4)));

// ---------- helpers ----------
__device__ __forceinline__ u16 f2bf(float f) {
  uint32_t u = __float_as_uint(f);
  u = (u + 0x7FFFu + ((u >> 16) & 1u)) >> 16;  // RNE
  return (u16)u;
}
__device__ __forceinline__ float bf2f(u16 x) {
  return __uint_as_float(((uint32_t)x) << 16);
}

__device__ __forceinline__ void gl2lds16(const void* g, void* l) {
  __builtin_amdgcn_global_load_lds(
      (const __attribute__((address_space(1))) void*)g,
      (__attribute__((address_space(3))) void*)l, 16, 0, 0);
}

// ---------- f32 -> bf16 array convert (n4 = count/4, exact) ----------
__global__ void cvt_bf16_arr(const float* __restrict__ in, u16* __restrict__ out, int n4) {
  int i = blockIdx.x * blockDim.x + threadIdx.x;
  if (i >= n4) return;
  float4 v = ((const float4*)in)[i];
  ushort4 o;
  o.x = f2bf(v.x); o.y = f2bf(v.y); o.z = f2bf(v.z); o.w = f2bf(v.w);
  ((ushort4*)out)[i] = o;
}

// ---------- pack Whh into the per-block swizzled LDS image ----------
// Block blk (of 8) owns rows n in [blk*64, blk*64+64). Image u16 index:
//   (n*64 + (c ^ (n&7)))*8 + e   holds  W[n][8c+e]   (c = 16B chunk, 0..63)
// Staged linearly into LDS -> read back with the same XOR -> bank-conflict-free.
__global__ void pack_whh_img(const float* __restrict__ W, u16* __restrict__ img) {
  int gid = blockIdx.x * 256 + threadIdx.x;   // 128 blocks * 256 thr = 32768
  int n = gid >> 6, c = gid & 63;
  const float* src = W + (long)n * 512 + c * 8;
  u16* dst = img + ((long)n * 64 + (c ^ (n & 7))) * 8;
  float4 v0 = *(const float4*)src;
  float4 v1 = *(const float4*)(src + 4);
  ushort4 o0, o1;
  o0.x = f2bf(v0.x); o0.y = f2bf(v0.y); o0.z = f2bf(v0.z); o0.w = f2bf(v0.w);
  o1.x = f2bf(v1.x); o1.y = f2bf(v1.y); o1.z = f2bf(v1.z); o1.w = f2bf(v1.w);
  *(ushort4*)dst = o0;
  *(ushort4*)(dst + 4) = o1;
}

// ---------- gather token embeddings -> bf16 rows (B-major, 128 per batch) ----------
__global__ void gather_embed(const int* __restrict__ tok, const float* __restrict__ embed,
                             u16* __restrict__ out, int tokStride) {
  int m = blockIdx.x;          // 0..4095 : b*128 + pos
  int t = threadIdx.x;         // 128 threads, 4 floats each
  int token = tok[(m >> 7) * tokStride + (m & 127)];
  float4 v = ((const float4*)(embed + (long)token * 512))[t];
  ushort4 o;
  o.x = f2bf(v.x); o.y = f2bf(v.y); o.z = f2bf(v.z); o.w = f2bf(v.w);
  ((ushort4*)(out + (long)m * 512))[t] = o;
}

// ---------- bf16 MFMA GEMM: C[M,N] = A[M,K] * B[N,K]^T (+bias[n]) ----------
// (round-1 verbatim; 128x128 tile, BK=32, 4 waves, 16x16x32 MFMA)
__global__ __launch_bounds__(256) void gemm_bf16_kernel(
    const u16* __restrict__ A, const u16* __restrict__ B,
    const float* __restrict__ bias, float* __restrict__ C,
    int M, int N, int K) {
  __shared__ __align__(16) u16 As[4096];
  __shared__ __align__(16) u16 Bs[4096];
  const int tid = threadIdx.x;
  const int lane = tid & 63;
  const int wv = tid >> 6;
  const int wr = wv >> 1, wc = wv & 1;
  const long m0 = (long)blockIdx.y * 128;
  const long n0 = (long)blockIdx.x * 128;

  f32x4 zero = {0.f, 0.f, 0.f, 0.f};
  f32x4 acc[4][4];
#pragma unroll
  for (int i = 0; i < 4; ++i)
#pragma unroll
    for (int j = 0; j < 4; ++j) acc[i][j] = zero;

  const u16* Ag = A + (m0 + (tid >> 2)) * (long)K + (tid & 3) * 8;
  const u16* Bg = B + (n0 + (tid >> 2)) * (long)K + (tid & 3) * 8;
  const u16* Ag2 = Ag + 64 * (long)K;
  const u16* Bg2 = Bg + 64 * (long)K;
  u16* AsW = As + (tid >> 6) * 512;   // wave-uniform LDS base
  u16* BsW = Bs + (tid >> 6) * 512;
  const int ra = (wr * 64 + (lane & 15)) * 32 + (lane >> 4) * 8;
  const int rb = (wc * 64 + (lane & 15)) * 32 + (lane >> 4) * 8;

  for (int kt = 0; kt < K; kt += 32) {
    __syncthreads();                         // previous-tile reads done
    gl2lds16(Ag + kt, AsW);                  // rows 0..63
    gl2lds16(Ag2 + kt, AsW + 2048);          // rows 64..127
    gl2lds16(Bg + kt, BsW);
    gl2lds16(Bg2 + kt, BsW + 2048);
    __syncthreads();                         // barrier drains vmcnt
    bf16x8 af[4], bfr[4];
#pragma unroll
    for (int i = 0; i < 4; ++i) af[i] = *(const bf16x8*)&As[ra + i * 512];
#pragma unroll
    for (int j = 0; j < 4; ++j) bfr[j] = *(const bf16x8*)&Bs[rb + j * 512];
#pragma unroll
    for (int i = 0; i < 4; ++i)
#pragma unroll
      for (int j = 0; j < 4; ++j)
        acc[i][j] = __builtin_amdgcn_mfma_f32_16x16x32_bf16(af[i], bfr[j], acc[i][j], 0, 0, 0);
  }

#pragma unroll
  for (int i = 0; i < 4; ++i) {
    const long row = m0 + wr * 64 + i * 16 + ((lane >> 4) << 2);
#pragma unroll
    for (int j = 0; j < 4; ++j) {
      const long col = n0 + wc * 64 + j * 16 + (lane & 15);
      const float bv = bias ? bias[col] : 0.f;
#pragma unroll
      for (int r = 0; r < 4; ++r)
        C[(row + r) * (long)N + col] = acc[i][j][r] + bv;
    }
  }
}

// ---------- RNN prep: init H ping-pong buf[0] (bf16) + reset step counter ----------
__global__ void rnn_prep(const float* __restrict__ h0, u16* __restrict__ Hbuf,
                         unsigned* __restrict__ counter) {
  int i = blockIdx.x * 256 + threadIdx.x;    // 64 blocks -> 16384
  if (i == 0) *counter = 0u;
  Hbuf[i] = h0 ? f2bf(h0[i]) : (u16)0;
}

// ---------- RNN recurrence v4: batched MFMA + LDS-resident weight slice ----------
// H_new[32,512] = tanh(Pre_t + H * Whh^T), one 32x512x512 GEMM per step.
// 8 blocks x 512 thr (8 waves = 2 M-tiles x 4 N-tiles). Block owns 64 output
// cols; its 64x512 Whh slice lives in LDS (64KB, XOR-swizzled image -> linear
// gl2lds staging, swizzled ds_read_b128 = conflict-free). H ping-pongs in a
// 2x32x512 bf16 global buffer (L2-resident). Cross-block step barrier =
// device-scope atomic counter + spin (8 blocks always co-resident).
__global__ __launch_bounds__(512) void rnn_mfma(
    const float* __restrict__ pre,            // [B*128][512] f32
    const u16* __restrict__ Wimg,             // swizzled weight image (512x512)
    const float* __restrict__ bih, const float* __restrict__ bhh,
    u16* __restrict__ Hbuf,                   // [2][32][512] bf16 ping-pong
    unsigned* __restrict__ counter,
    float* __restrict__ hOutF, long ldF,      // f32 h out (or null)
    u16* __restrict__ hOutB, long ldB_,       // bf16 h out
    float* __restrict__ hLast)                // [B][512] f32 or null
{
  const int blk = blockIdx.x;                 // 0..7
  const int tid = threadIdx.x, lane = tid & 63, w = tid >> 6;
  const int mi = w >> 2, nt = w & 3;          // wave tile: M 0..1, N 0..3
  __shared__ __align__(16) u16 wlds[32768];   // 64 KB

  // stage this block's 64KB weight slice, 8KB per wave, linear
  {
    const u16* src = Wimg + (long)blk * 32768 + w * 4096 + lane * 8;
    u16* dst = wlds + w * 4096;
#pragma unroll
    for (int c = 0; c < 8; ++c)
      gl2lds16(src + c * 512, dst + c * 512);
  }
  const int rq = lane >> 4;                   // 0..3
  const int nl = nt * 16 + (lane & 15);       // local n (0..63)
  const int nCol = blk * 64 + nl;             // global n (0..511)
  const float biasv = bih[nCol] + bhh[nCol];
  const int rowA = mi * 16 + (lane & 15);     // A-frag row (batch)
  const int bRow0 = mi * 16 + rq * 4;         // epilogue batch base
  __syncthreads();                            // weights staged (barrier drains vmcnt)

  for (int t = 0; t < 128; ++t) {
    const u16* cur = Hbuf + (t & 1) * 16384;
    u16* nxt = Hbuf + ((t + 1) & 1) * 16384;
    const u16* aptr = cur + rowA * 512 + rq * 8;
    f32x4 acc = {0.f, 0.f, 0.f, 0.f};
#pragma unroll
    for (int ks = 0; ks < 16; ++ks) {
      bf16x8 av = *(const bf16x8*)(aptr + ks * 32);           // global (L2-hot)
      int boff = nl * 1024 + (((ks * 4 + rq) ^ (nl & 7)) << 4);
      bf16x8 bv = *(const bf16x8*)((const char*)wlds + boff); // LDS, swizzled
      acc = __builtin_amdgcn_mfma_f32_16x16x32_bf16(av, bv, acc, 0, 0, 0);
    }
    // epilogue: h = tanh(acc + pre + bias); C/D layout row=(lane>>4)*4+i, col=lane&15
#pragma unroll
    for (int i = 0; i < 4; ++i) {
      int b = bRow0 + i;
      float h = tanhf(acc[i] + pre[((long)b * 128 + t) * 512 + nCol] + biasv);
      u16 hb = f2bf(h);
      nxt[b * 512 + nCol] = hb;
      hOutB[((long)b * 128 + t) * ldB_ + nCol] = hb;
      if (hOutF) hOutF[((long)b * 128 + t) * ldF + nCol] = h;
      if (hLast && t == 127) hLast[(long)b * 512 + nCol] = h;
    }
    // cross-block step barrier: release -> count -> spin -> acquire
    __threadfence();
    __syncthreads();
    if (tid == 0) {
      atomicAdd(counter, 1u);
      while (atomicAdd(counter, 0u) < 8u * (unsigned)(t + 1))
        __builtin_amdgcn_s_sleep(2);
    }
    __syncthreads();
    __threadfence();
  }
}

// ---------- fused attention: scores -> softmax -> att out -> ctx (all f32) ----------
// grid (32 b, 8 t-groups), block 1024 (16 waves, wave w owns t = y*16+w)
__global__ __launch_bounds__(1024) void attn_fused(
    const u16* __restrict__ hcat,        // bf16, dec_h in cols 0..511
    const float* __restrict__ encT,      // [B][128 s][512] f32
    const float* __restrict__ encBsh,    // [B][128 s][512] f32
    u16* __restrict__ hcatW,             // write ctx into cols 512..1023 (bf16)
    float* __restrict__ attOut)          // [B][128 s][128 t] f32
{
  const int b = blockIdx.x;
  const int w = threadIdx.x >> 6, lane = threadIdx.x & 63;
  const int t = blockIdx.y * 16 + w;
  __shared__ float at[16][128];

  // dec_h row t -> registers (bf16 -> f32)
  float hreg[8];
  const u16* hrow = hcat + ((long)b * 128 + t) * 1024;
#pragma unroll
  for (int i = 0; i < 8; ++i) hreg[i] = bf2f(hrow[lane + i * 64]);

  // scores: score[s] = dec_h[t] . enc_t[s]
  const float* et = encT + (long)b * 128 * 512;
  for (int s = 0; s < 128; ++s) {
    const float* row = et + (long)s * 512;
    float a = 0.f;
#pragma unroll
    for (int i = 0; i < 8; ++i) a += hreg[i] * row[lane + i * 64];
#pragma unroll
    for (int o = 32; o; o >>= 1) a += __shfl_xor(a, o, 64);
    if (lane == 0) at[w][s] = a;
  }
  __syncthreads();

  // softmax over s (per wave, 2 values per lane)
  float s0 = at[w][lane], s1 = at[w][lane + 64];
  float mx = fmaxf(s0, s1);
#pragma unroll
  for (int o = 32; o; o >>= 1) mx = fmaxf(mx, __shfl_xor(mx, o, 64));
  float e0 = __expf(s0 - mx), e1 = __expf(s1 - mx);
  float sm = e0 + e1;
#pragma unroll
  for (int o = 32; o; o >>= 1) sm += __shfl_xor(sm, o, 64);
  float inv = 1.f / sm;
  e0 *= inv; e1 *= inv;
  at[w][lane] = e0;
  at[w][lane + 64] = e1;
  __syncthreads();

  // att output: att[b][s][t]
  attOut[(long)b * 16384 + (long)lane * 128 + t] = e0;
  attOut[(long)b * 16384 + (long)(lane + 64) * 128 + t] = e1;

  // ctx[t][:] = sum_s attn[s] * enc_bsh[s][:]
  float acc[8] = {0.f, 0.f, 0.f, 0.f, 0.f, 0.f, 0.f, 0.f};
  const float* eb = encBsh + (long)b * 128 * 512;
  for (int s = 0; s < 128; ++s) {
    float ws = at[w][s];
    const float* row = eb + (long)s * 512;
#pragma unroll
    for (int i = 0; i < 8; ++i) acc[i] += ws * row[lane + i * 64];
  }
  u16* crow = hcatW + ((long)b * 128 + t) * 1024 + 512;
#pragma unroll
  for (int i = 0; i < 8; ++i) crow[lane + i * 64] = f2bf(acc[i]);
}

// ---------- launcher ----------
extern "C" void kernel_launch(void* const* d_in, const int* in_sizes, int n_in,
                              void* d_out, int out_size, void* d_ws, size_t ws_size,
                              hipStream_t stream) {
  (void)in_sizes; (void)n_in; (void)out_size; (void)ws_size;
  const int*   source = (const int*)d_in[0];
  const int*   target = (const int*)d_in[1];
  const float* embed  = (const float*)d_in[2];
  const float* encWih = (const float*)d_in[3];
  const float* encWhh = (const float*)d_in[4];
  const float* encBih = (const float*)d_in[5];
  const float* encBhh = (const float*)d_in[6];
  const float* decWih = (const float*)d_in[7];
  const float* decWhh = (const float*)d_in[8];
  const float* decBih = (const float*)d_in[9];
  const float* decBhh = (const float*)d_in[10];
  const float* attnW  = (const float*)d_in[11];
  const float* attnB  = (const float*)d_in[12];
  const float* outW   = (const float*)d_in[13];
  const float* outB   = (const float*)d_in[14];

  float* out_logits = (float*)d_out;
  float* out_att = out_logits + (long)32 * 128 * 32000;

  char* wsb = (char*)d_ws;
  size_t off = 0;
  auto alloc = [&](size_t bytes) {
    char* p = wsb + off;
    off += (bytes + 255) & ~(size_t)255;
    return p;
  };
  u16*      encA   = (u16*)alloc(4096l * 512 * 2);
  u16*      decA   = (u16*)alloc(4096l * 512 * 2);
  u16*      wihE   = (u16*)alloc(512l * 512 * 2);
  u16*      wihD   = (u16*)alloc(512l * 512 * 2);
  u16*      attnWb = (u16*)alloc(512l * 512 * 2);
  u16*      wimgE  = (u16*)alloc(512l * 512 * 2);   // swizzled Whh images
  u16*      wimgD  = (u16*)alloc(512l * 512 * 2);
  u16*      outWb  = (u16*)alloc(32000l * 1024 * 2);
  float*    preE   = (float*)alloc(4096l * 512 * 4);
  float*    preD   = (float*)alloc(4096l * 512 * 4);
  float*    encBsh = (float*)alloc(4096l * 512 * 4);
  u16*      encBf  = (u16*)alloc(4096l * 512 * 2);
  float*    encT   = (float*)alloc(4096l * 512 * 4);
  float*    hlast  = (float*)alloc(32l * 512 * 4);
  u16*      hcat   = (u16*)alloc(4096l * 1024 * 2);
  u16*      HbufE  = (u16*)alloc(2l * 32 * 512 * 2);
  u16*      HbufD  = (u16*)alloc(2l * 32 * 512 * 2);
  unsigned* ctrE   = (unsigned*)alloc(256);
  unsigned* ctrD   = (unsigned*)alloc(256);

  // weight conversions (independent)
  cvt_bf16_arr<<<256, 256, 0, stream>>>(encWih, wihE, 65536);
  cvt_bf16_arr<<<256, 256, 0, stream>>>(decWih, wihD, 65536);
  cvt_bf16_arr<<<256, 256, 0, stream>>>(attnW, attnWb, 65536);
  cvt_bf16_arr<<<32000, 256, 0, stream>>>(outW, outWb, 8192000);
  pack_whh_img<<<128, 256, 0, stream>>>(encWhh, wimgE);
  pack_whh_img<<<128, 256, 0, stream>>>(decWhh, wimgD);
  // embedding gathers
  gather_embed<<<4096, 128, 0, stream>>>(source, embed, encA, 128);
  gather_embed<<<4096, 128, 0, stream>>>(target, embed, decA, 129);
  // pre-activations for all timesteps: x @ Wih^T (f32 out)
  gemm_bf16_kernel<<<dim3(4, 32), 256, 0, stream>>>(encA, wihE, (const float*)nullptr, preE, 4096, 512, 512);
  gemm_bf16_kernel<<<dim3(4, 32), 256, 0, stream>>>(decA, wihD, (const float*)nullptr, preD, 4096, 512, 512);
  // encoder recurrence (h0=0): writes encBsh f32, encBf bf16, hlast f32
  rnn_prep<<<64, 256, 0, stream>>>((const float*)nullptr, HbufE, ctrE);
  rnn_mfma<<<8, 512, 0, stream>>>(preE, wimgE, encBih, encBhh, HbufE, ctrE,
      encBsh, 512, encBf, 512, hlast);
  // enc_t = enc_h @ attn_W^T + attn_b (f32 out)
  gemm_bf16_kernel<<<dim3(4, 32), 256, 0, stream>>>(encBf, attnWb, attnB, encT, 4096, 512, 512);
  // decoder recurrence (h0 = enc last): writes dec_h bf16 into hcat left half
  rnn_prep<<<64, 256, 0, stream>>>(hlast, HbufD, ctrD);
  rnn_mfma<<<8, 512, 0, stream>>>(preD, wimgD, decBih, decBhh, HbufD, ctrD,
      (float*)nullptr, 512, hcat, 1024, (float*)nullptr);
  // fused attention: scores->softmax->att out->ctx (f32), ctx bf16 -> hcat right half
  attn_fused<<<dim3(32, 8), 1024, 0, stream>>>(hcat, encT, encBsh, hcat, out_att);
  // logits = [h,ctx] @ out_W^T + out_b  -> d_out (B,T,C) f32
  gemm_bf16_kernel<<<dim3(250, 32), 256, 0, stream>>>(hcat, outWb, outB, out_logits, 4096, 32000, 1024);
}